// Round 13
// baseline (514.997 us; speedup 1.0000x reference)
//
#include <hip/hip_runtime.h>
#include <hip/hip_bf16.h>

#define N_NODES 50000
#define N_EDGES 800000
#define HID 128

typedef __attribute__((ext_vector_type(8))) short bf16x8;
typedef __attribute__((ext_vector_type(4))) float f32x4;

__device__ inline ushort f32_to_bf16_bits(float v) {
    union { float f; unsigned u; } a; a.f = v;
    unsigned r = a.u + 0x7fff + ((a.u >> 16) & 1);  // RNE
    return (ushort)(r >> 16);
}
__device__ inline float bf16bits_to_f32(ushort b) {
    union { float f; unsigned u; } a; a.u = ((unsigned)b) << 16;
    return a.f;
}

// ---------------- prologue: conv(feat->bf16) + prep(weights) + hist ----------------

__global__ __launch_bounds__(256) void prologue_kernel(const float* __restrict__ feat,
                                                       const int* __restrict__ dst,
                                                       const float* __restrict__ W1a,
                                                       const float* __restrict__ W2a,
                                                       const float* __restrict__ Ws1,
                                                       const float* __restrict__ Ws2,
                                                       ushort* __restrict__ xbA,
                                                       short* __restrict__ whi,
                                                       short* __restrict__ wlo,
                                                       int* __restrict__ cnt) {
    const int gtid = blockIdx.x * 256 + threadIdx.x;   // grid 1024*256 = 262144
    const int GS = 262144;

    // ---- phase A: feat f32 -> bf16 table ----
    for (int t = gtid; t < 800000; t += GS) {
        const float4* in4 = (const float4*)feat;
        float4 a = in4[2 * t], b = in4[2 * t + 1];
        float v[8] = {a.x, a.y, a.z, a.w, b.x, b.y, b.z, b.w};
        uint4 o;
        o.x = (unsigned)f32_to_bf16_bits(v[0]) | ((unsigned)f32_to_bf16_bits(v[1]) << 16);
        o.y = (unsigned)f32_to_bf16_bits(v[2]) | ((unsigned)f32_to_bf16_bits(v[3]) << 16);
        o.z = (unsigned)f32_to_bf16_bits(v[4]) | ((unsigned)f32_to_bf16_bits(v[5]) << 16);
        o.w = (unsigned)f32_to_bf16_bits(v[6]) | ((unsigned)f32_to_bf16_bits(v[7]) << 16);
        ((uint4*)xbA)[t] = o;
    }

    // ---- phase B: weight prep, fragment-linear hi/lo (6 mats x 2048 threads) ----
    // Shared (lane,elem)->k rule for A and B packing => k-permutation cancels.
    if (gtid < 6 * 2048) {
        int mat = gtid >> 11;
        int tid2 = gtid & 2047;
        const float* W;
        switch (mat) {
            case 0: W = W1a; break;
            case 1: W = W2a; break;
            case 2: W = Ws1; break;
            case 3: W = Ws2; break;
            case 4: W = Ws1 + HID * HID; break;
            default: W = Ws2 + HID * HID; break;
        }
        int l = tid2 & 63;
        int ft = tid2 >> 6;
        int t = ft & 3, f = ft >> 2;
        int g = l >> 4, lm = l & 15;
        bf16x8 hv, lv;
        #pragma unroll
        for (int i = 0; i < 8; ++i) {
            int k = t * 32 + g * 8 + i;
            int n = f * 16 + lm;
            float v = W[k * HID + n];
            ushort hb = f32_to_bf16_bits(v);
            ushort lb = f32_to_bf16_bits(v - bf16bits_to_f32(hb));
            hv[i] = (short)hb;
            lv[i] = (short)lb;
        }
        size_t base = ((size_t)mat * 2048 + tid2) * 8;
        *(bf16x8*)&whi[base] = hv;
        *(bf16x8*)&wlo[base] = lv;
    }

    // ---- phase C: degree histogram ----
    for (int e = gtid; e < N_EDGES; e += GS) {
        atomicAdd(&cnt[dst[e]], 1);
    }
}

// ---------------- CSR offsets (wave-scan allocation) + bucket cursors ----------------
// INVARIANT: each 64-node aligned group == one wave's allocation == one CONTIGUOUS
// CSR region [offs[64b], offs[64b]+sum(cnt)). Buckets MUST be 64 nodes (r12 bug:
// 128-node buckets spanned two waves whose regions are not adjacent).

__global__ __launch_bounds__(256) void alloc_offsets_kernel(const int* __restrict__ cnt,
                                                            int* __restrict__ offs,
                                                            int* __restrict__ cursor,
                                                            int* __restrict__ gcur,
                                                            int* __restrict__ bcur) {
    int i = blockIdx.x * 256 + threadIdx.x;
    int lane = threadIdx.x & 63;
    int c = (i < N_NODES) ? cnt[i] : 0;
    int pre = c;
    #pragma unroll
    for (int d = 1; d < 64; d <<= 1) {
        int t = __shfl_up(pre, d);
        if (lane >= d) pre += t;
    }
    int base = 0;
    if (lane == 63) base = atomicAdd(gcur, pre);
    base = __shfl(base, 63);
    int o = base + pre - c;
    if (i < N_NODES) {
        offs[i] = o;
        cursor[i] = o;
        if (lane == 0) bcur[i >> 6] = o;   // bucket b (64 nodes) starts at offs[64b]
    }
}

// ---------------- pass 1: partition edges into 64-node buckets ----------------
// staging[p] = src | dst<<16, p allocated from the bucket's monotone cursor.
// Bucket region is contiguous (one wave's CSR region) -> writes cluster, low amp.

__global__ __launch_bounds__(256) void partition_kernel(const int* __restrict__ src,
                                                        const int* __restrict__ dst,
                                                        int* __restrict__ bcur,
                                                        unsigned* __restrict__ staging) {
    int e = blockIdx.x * 256 + threadIdx.x;
    if (e < N_EDGES) {
        int d = dst[e];
        int s = src[e];
        int p = atomicAdd(&bcur[d >> 6], 1);
        staging[p] = (unsigned)s | ((unsigned)d << 16);
    }
}

// ---------------- pass 2: bucket-local scatter to final CSR positions ----------------
// Sequential staging reads; same-bucket entries contiguous -> csr writes land in
// one ~2KB L2-resident window per bucket -> full-line fills.

__global__ __launch_bounds__(256) void scatter2_kernel(const unsigned* __restrict__ staging,
                                                       int* __restrict__ cursor,
                                                       ushort* __restrict__ csr16) {
    int p = blockIdx.x * 256 + threadIdx.x;
    if (p < N_EDGES) {
        unsigned v = staging[p];
        int s = v & 0xffff;
        int d = v >> 16;
        int pos = atomicAdd(&cursor[d], 1);
        csr16[pos] = (ushort)s;
    }
}

// ---------------- fused GIN layer: out = relu(mlp(x + sum_{j->i} x_j)) ----------------
// 256 thr = 4 waves per block, 16 nodes/block (grid 3125 -> ~32 waves/CU).

__global__ __launch_bounds__(256) void fused_gin_kernel(const unsigned* __restrict__ xbf,
                                                        const ushort* __restrict__ csr16,
                                                        const int* __restrict__ offs,
                                                        const int* __restrict__ cnt,
                                                        const short* __restrict__ w1hi,
                                                        const short* __restrict__ w1lo,
                                                        const short* __restrict__ w2hi,
                                                        const short* __restrict__ w2lo,
                                                        const float* __restrict__ b1,
                                                        const float* __restrict__ b2,
                                                        ushort* __restrict__ xoutb,
                                                        float* __restrict__ xoutf) {
    __shared__ short sHi[16][136];
    __shared__ short sLo[16][136];

    const int tid = threadIdx.x;
    const int lane = tid & 63;
    const int wid = tid >> 6;
    const int nbase = blockIdx.x * 16;     // 3125 * 16 == 50000 exactly
    const int g = lane >> 4, lm = lane & 15;

    // ---- gather phase: h[n] = x[n] + sum_j x[csr[j]] (bf16 in, f32 accum) ----
    for (int n = 0; n < 4; ++n) {
        int node = nbase + wid * 4 + n;
        int off = offs[node];
        int c = cnt[node];
        unsigned su = xbf[(size_t)node * 64 + lane];   // cols {2l, 2l+1}
        float ax = __uint_as_float(su << 16);
        float ay = __uint_as_float(su & 0xffff0000u);
        int e = 0;
        for (; e + 16 <= c; e += 16) {
            int s[16];
            #pragma unroll
            for (int q = 0; q < 16; ++q) s[q] = csr16[off + e + q];
            unsigned u[16];
            #pragma unroll
            for (int q = 0; q < 16; ++q) u[q] = xbf[(size_t)s[q] * 64 + lane];
            #pragma unroll
            for (int q = 0; q < 16; ++q) {
                ax += __uint_as_float(u[q] << 16);
                ay += __uint_as_float(u[q] & 0xffff0000u);
            }
        }
        for (; e + 4 <= c; e += 4) {
            int s0 = csr16[off + e], s1 = csr16[off + e + 1];
            int s2 = csr16[off + e + 2], s3 = csr16[off + e + 3];
            unsigned u0 = xbf[(size_t)s0 * 64 + lane];
            unsigned u1 = xbf[(size_t)s1 * 64 + lane];
            unsigned u2 = xbf[(size_t)s2 * 64 + lane];
            unsigned u3 = xbf[(size_t)s3 * 64 + lane];
            ax += (__uint_as_float(u0 << 16) + __uint_as_float(u1 << 16)) +
                  (__uint_as_float(u2 << 16) + __uint_as_float(u3 << 16));
            ay += (__uint_as_float(u0 & 0xffff0000u) + __uint_as_float(u1 & 0xffff0000u)) +
                  (__uint_as_float(u2 & 0xffff0000u) + __uint_as_float(u3 & 0xffff0000u));
        }
        for (; e < c; ++e) {
            int s = csr16[off + e];
            unsigned u = xbf[(size_t)s * 64 + lane];
            ax += __uint_as_float(u << 16);
            ay += __uint_as_float(u & 0xffff0000u);
        }
        ushort hx = f32_to_bf16_bits(ax);
        ushort lx = f32_to_bf16_bits(ax - bf16bits_to_f32(hx));
        ushort hy = f32_to_bf16_bits(ay);
        ushort ly = f32_to_bf16_bits(ay - bf16bits_to_f32(hy));
        int row = wid * 4 + n;
        *(unsigned*)&sHi[row][2 * lane] = (unsigned)hx | ((unsigned)hy << 16);
        *(unsigned*)&sLo[row][2 * lane] = (unsigned)lx | ((unsigned)ly << 16);
    }
    __syncthreads();

    f32x4 accT[2];

    // ---- GEMM1: T = relu(h @ W1 + b1), wave computes f = {2*wid, 2*wid+1} ----
    {
        bf16x8 ahi[4], alo[4];
        #pragma unroll
        for (int t = 0; t < 4; ++t) {
            ahi[t] = *(bf16x8*)&sHi[lm][t * 32 + g * 8];
            alo[t] = *(bf16x8*)&sLo[lm][t * 32 + g * 8];
        }
        __syncthreads();   // all waves have read h before epilogue overwrites
        #pragma unroll
        for (int ff = 0; ff < 2; ++ff) {
            int f = wid * 2 + ff;
            const bf16x8* bh = (const bf16x8*)&w1hi[((size_t)(f * 4) * 64 + lane) * 8];
            const bf16x8* bl = (const bf16x8*)&w1lo[((size_t)(f * 4) * 64 + lane) * 8];
            f32x4 acc = {0.f, 0.f, 0.f, 0.f};
            #pragma unroll
            for (int t = 0; t < 4; ++t) {
                bf16x8 bhv = bh[t * 64];
                bf16x8 blv = bl[t * 64];
                acc = __builtin_amdgcn_mfma_f32_16x16x32_bf16(ahi[t], bhv, acc, 0, 0, 0);
                acc = __builtin_amdgcn_mfma_f32_16x16x32_bf16(alo[t], bhv, acc, 0, 0, 0);
                acc = __builtin_amdgcn_mfma_f32_16x16x32_bf16(ahi[t], blv, acc, 0, 0, 0);
            }
            accT[ff] = acc;
        }
    }
    // epilogue 1: bias+relu, split hi/lo, write back (C/D: row=g*4+r, col=f*16+lm)
    #pragma unroll
    for (int ff = 0; ff < 2; ++ff) {
        int f = wid * 2 + ff;
        float bv = b1[f * 16 + lm];
        #pragma unroll
        for (int r = 0; r < 4; ++r) {
            float v = accT[ff][r] + bv;
            v = v > 0.f ? v : 0.f;
            ushort hb = f32_to_bf16_bits(v);
            ushort lb = f32_to_bf16_bits(v - bf16bits_to_f32(hb));
            int m = g * 4 + r;
            sHi[m][f * 16 + lm] = (short)hb;
            sLo[m][f * 16 + lm] = (short)lb;
        }
    }
    __syncthreads();

    // ---- GEMM2: out = relu(T @ W2 + b2) ----
    {
        bf16x8 ahi[4], alo[4];
        #pragma unroll
        for (int t = 0; t < 4; ++t) {
            ahi[t] = *(bf16x8*)&sHi[lm][t * 32 + g * 8];
            alo[t] = *(bf16x8*)&sLo[lm][t * 32 + g * 8];
        }
        #pragma unroll
        for (int ff = 0; ff < 2; ++ff) {
            int f = wid * 2 + ff;
            const bf16x8* bh = (const bf16x8*)&w2hi[((size_t)(f * 4) * 64 + lane) * 8];
            const bf16x8* bl = (const bf16x8*)&w2lo[((size_t)(f * 4) * 64 + lane) * 8];
            f32x4 acc = {0.f, 0.f, 0.f, 0.f};
            #pragma unroll
            for (int t = 0; t < 4; ++t) {
                bf16x8 bhv = bh[t * 64];
                bf16x8 blv = bl[t * 64];
                acc = __builtin_amdgcn_mfma_f32_16x16x32_bf16(ahi[t], bhv, acc, 0, 0, 0);
                acc = __builtin_amdgcn_mfma_f32_16x16x32_bf16(alo[t], bhv, acc, 0, 0, 0);
                acc = __builtin_amdgcn_mfma_f32_16x16x32_bf16(ahi[t], blv, acc, 0, 0, 0);
            }
            accT[ff] = acc;
        }
    }
    // epilogue 2: bias+relu; store bf16 (next-layer gather) and/or f32 (final)
    #pragma unroll
    for (int ff = 0; ff < 2; ++ff) {
        int f = wid * 2 + ff;
        float bv = b2[f * 16 + lm];
        #pragma unroll
        for (int r = 0; r < 4; ++r) {
            float v = accT[ff][r] + bv;
            v = v > 0.f ? v : 0.f;
            int gn = nbase + g * 4 + r;
            size_t gi = (size_t)gn * HID + f * 16 + lm;
            if (xoutb) xoutb[gi] = f32_to_bf16_bits(v);
            if (xoutf) xoutf[gi] = v;
        }
    }
}

// ---------------- launch ----------------

extern "C" void kernel_launch(void* const* d_in, const int* in_sizes, int n_in,
                              void* d_out, int out_size, void* d_ws, size_t ws_size,
                              hipStream_t stream) {
    const float* feat = (const float*)d_in[0];
    const int* edge = (const int*)d_in[1];
    const int* src = edge;
    const int* dst = edge + N_EDGES;
    const float* W1a = (const float*)d_in[2];
    const float* b1a = (const float*)d_in[3];
    const float* W2a = (const float*)d_in[4];
    const float* b2a = (const float*)d_in[5];
    const float* Ws1 = (const float*)d_in[6];
    const float* bs1 = (const float*)d_in[7];
    const float* Ws2 = (const float*)d_in[8];
    const float* bs2 = (const float*)d_in[9];
    float* out = (float*)d_out;

    // ws layout (ints/halves, in order):
    //   cnt(50176 i32) | gcur(64 i32) | bcur(784 i32) | offs(50176) | cursor(50176)
    //   | csr16(800000 u16) | staging(800000 u32) | xbA(6.4M u16) | xbB | whi | wlo
    int* cnt = (int*)d_ws;
    int* gcur = cnt + 50176;
    int* bcur = gcur + 64;
    int* offs = bcur + 784;
    int* cursor = offs + 50176;
    ushort* csr16 = (ushort*)(cursor + 50176);
    unsigned* staging = (unsigned*)(csr16 + N_EDGES);
    ushort* xbA = (ushort*)(staging + N_EDGES);
    ushort* xbB = xbA + (size_t)N_NODES * HID;
    short* whi = (short*)(xbB + (size_t)N_NODES * HID);
    short* wlo = whi + 6 * 2048 * 8;

    hipMemsetAsync(cnt, 0, (50176 + 64) * sizeof(int), stream);

    prologue_kernel<<<1024, 256, 0, stream>>>(feat, dst, W1a, W2a, Ws1, Ws2,
                                              xbA, whi, wlo, cnt);
    alloc_offsets_kernel<<<(N_NODES + 255) / 256, 256, 0, stream>>>(cnt, offs, cursor,
                                                                    gcur, bcur);
    partition_kernel<<<(N_EDGES + 255) / 256, 256, 0, stream>>>(src, dst, bcur, staging);
    scatter2_kernel<<<(N_EDGES + 255) / 256, 256, 0, stream>>>(staging, cursor, csr16);

    const int FB = N_NODES / 16;   // 3125 blocks, 16 nodes each, exact
    const int MS = 16384;          // per-matrix fragment array size (shorts)

    // mat order: W1a, W2a, Ws1[0], Ws2[0], Ws1[1], Ws2[1]
    // buffers: A(feat) -> B -> A -> d_out
    fused_gin_kernel<<<FB, 256, 0, stream>>>((const unsigned*)xbA, csr16, offs, cnt,
                                             whi + 0 * MS, wlo + 0 * MS,
                                             whi + 1 * MS, wlo + 1 * MS, b1a, b2a,
                                             xbB, nullptr);
    fused_gin_kernel<<<FB, 256, 0, stream>>>((const unsigned*)xbB, csr16, offs, cnt,
                                             whi + 2 * MS, wlo + 2 * MS,
                                             whi + 3 * MS, wlo + 3 * MS, bs1, bs2,
                                             xbA, nullptr);
    fused_gin_kernel<<<FB, 256, 0, stream>>>((const unsigned*)xbA, csr16, offs, cnt,
                                             whi + 4 * MS, wlo + 4 * MS,
                                             whi + 5 * MS, wlo + 5 * MS,
                                             bs1 + HID, bs2 + HID,
                                             nullptr, out);
}

// Round 14
// 323.266 us; speedup vs baseline: 1.5931x; 1.5931x over previous
//
#include <hip/hip_runtime.h>
#include <hip/hip_bf16.h>

#define N_NODES 50000
#define N_EDGES 800000
#define HID 128

typedef __attribute__((ext_vector_type(8))) short bf16x8;
typedef __attribute__((ext_vector_type(4))) float f32x4;

__device__ inline ushort f32_to_bf16_bits(float v) {
    union { float f; unsigned u; } a; a.f = v;
    unsigned r = a.u + 0x7fff + ((a.u >> 16) & 1);  // RNE
    return (ushort)(r >> 16);
}
__device__ inline float bf16bits_to_f32(ushort b) {
    union { float f; unsigned u; } a; a.u = ((unsigned)b) << 16;
    return a.f;
}

// ---------------- prologue: conv(feat->bf16) + prep(weights) + hist ----------------

__global__ __launch_bounds__(256) void prologue_kernel(const float* __restrict__ feat,
                                                       const int* __restrict__ dst,
                                                       const float* __restrict__ W1a,
                                                       const float* __restrict__ W2a,
                                                       const float* __restrict__ Ws1,
                                                       const float* __restrict__ Ws2,
                                                       ushort* __restrict__ xbA,
                                                       short* __restrict__ whi,
                                                       short* __restrict__ wlo,
                                                       int* __restrict__ cnt) {
    const int gtid = blockIdx.x * 256 + threadIdx.x;   // grid 1024*256 = 262144
    const int GS = 262144;

    // ---- phase A: feat f32 -> bf16 table ----
    for (int t = gtid; t < 800000; t += GS) {
        const float4* in4 = (const float4*)feat;
        float4 a = in4[2 * t], b = in4[2 * t + 1];
        float v[8] = {a.x, a.y, a.z, a.w, b.x, b.y, b.z, b.w};
        uint4 o;
        o.x = (unsigned)f32_to_bf16_bits(v[0]) | ((unsigned)f32_to_bf16_bits(v[1]) << 16);
        o.y = (unsigned)f32_to_bf16_bits(v[2]) | ((unsigned)f32_to_bf16_bits(v[3]) << 16);
        o.z = (unsigned)f32_to_bf16_bits(v[4]) | ((unsigned)f32_to_bf16_bits(v[5]) << 16);
        o.w = (unsigned)f32_to_bf16_bits(v[6]) | ((unsigned)f32_to_bf16_bits(v[7]) << 16);
        ((uint4*)xbA)[t] = o;
    }

    // ---- phase B: weight prep, fragment-linear hi/lo (6 mats x 2048 threads) ----
    // Shared (lane,elem)->k rule for A and B packing => k-permutation cancels.
    if (gtid < 6 * 2048) {
        int mat = gtid >> 11;
        int tid2 = gtid & 2047;
        const float* W;
        switch (mat) {
            case 0: W = W1a; break;
            case 1: W = W2a; break;
            case 2: W = Ws1; break;
            case 3: W = Ws2; break;
            case 4: W = Ws1 + HID * HID; break;
            default: W = Ws2 + HID * HID; break;
        }
        int l = tid2 & 63;
        int ft = tid2 >> 6;
        int t = ft & 3, f = ft >> 2;
        int g = l >> 4, lm = l & 15;
        bf16x8 hv, lv;
        #pragma unroll
        for (int i = 0; i < 8; ++i) {
            int k = t * 32 + g * 8 + i;
            int n = f * 16 + lm;
            float v = W[k * HID + n];
            ushort hb = f32_to_bf16_bits(v);
            ushort lb = f32_to_bf16_bits(v - bf16bits_to_f32(hb));
            hv[i] = (short)hb;
            lv[i] = (short)lb;
        }
        size_t base = ((size_t)mat * 2048 + tid2) * 8;
        *(bf16x8*)&whi[base] = hv;
        *(bf16x8*)&wlo[base] = lv;
    }

    // ---- phase C: degree histogram ----
    for (int e = gtid; e < N_EDGES; e += GS) {
        atomicAdd(&cnt[dst[e]], 1);
    }
}

// ---------------- CSR offsets (wave-scan allocation) ----------------

__global__ __launch_bounds__(256) void alloc_offsets_kernel(const int* __restrict__ cnt,
                                                            int* __restrict__ offs,
                                                            int* __restrict__ cursor,
                                                            int* __restrict__ gcur) {
    int i = blockIdx.x * 256 + threadIdx.x;
    int lane = threadIdx.x & 63;
    int c = (i < N_NODES) ? cnt[i] : 0;
    int pre = c;
    #pragma unroll
    for (int d = 1; d < 64; d <<= 1) {
        int t = __shfl_up(pre, d);
        if (lane >= d) pre += t;
    }
    int base = 0;
    if (lane == 63) base = atomicAdd(gcur, pre);
    base = __shfl(base, 63);
    int o = base + pre - c;
    if (i < N_NODES) { offs[i] = o; cursor[i] = o; }
}

// ---------------- scatter: csr16[pos] = src, single-pass, plain stores ----------------
// r13 lesson: few-bucket atomic allocation is contention-bound (1020 serialized
// atomics/address = 192us) and cross-XCD line sharing defeats write clustering.
// 50k cursors (16 edges/addr) + random line writes ~52us / ~51MB is the floor.

__global__ __launch_bounds__(256) void scatter_kernel(const int* __restrict__ src,
                                                      const int* __restrict__ dst,
                                                      int* __restrict__ cursor,
                                                      ushort* __restrict__ csr16) {
    int e = blockIdx.x * 256 + threadIdx.x;
    if (e < N_EDGES) {
        int d = dst[e];
        int s = src[e];
        int pos = atomicAdd(&cursor[d], 1);
        csr16[pos] = (ushort)s;
    }
}

// ---------------- fused GIN layer: out = relu(mlp(x + sum_{j->i} x_j)) ----------------
// 256 thr = 4 waves per block, 16 nodes/block (grid 3125 -> ~32 waves/CU).

__global__ __launch_bounds__(256) void fused_gin_kernel(const unsigned* __restrict__ xbf,
                                                        const ushort* __restrict__ csr16,
                                                        const int* __restrict__ offs,
                                                        const int* __restrict__ cnt,
                                                        const short* __restrict__ w1hi,
                                                        const short* __restrict__ w1lo,
                                                        const short* __restrict__ w2hi,
                                                        const short* __restrict__ w2lo,
                                                        const float* __restrict__ b1,
                                                        const float* __restrict__ b2,
                                                        ushort* __restrict__ xoutb,
                                                        float* __restrict__ xoutf) {
    __shared__ short sHi[16][136];
    __shared__ short sLo[16][136];

    const int tid = threadIdx.x;
    const int lane = tid & 63;
    const int wid = tid >> 6;
    const int nbase = blockIdx.x * 16;     // 3125 * 16 == 50000 exactly
    const int g = lane >> 4, lm = lane & 15;

    // ---- gather phase: h[n] = x[n] + sum_j x[csr[j]] (bf16 in, f32 accum) ----
    for (int n = 0; n < 4; ++n) {
        int node = nbase + wid * 4 + n;
        int off = offs[node];
        int c = cnt[node];
        unsigned su = xbf[(size_t)node * 64 + lane];   // cols {2l, 2l+1}
        float ax = __uint_as_float(su << 16);
        float ay = __uint_as_float(su & 0xffff0000u);
        int e = 0;
        for (; e + 16 <= c; e += 16) {
            int s[16];
            #pragma unroll
            for (int q = 0; q < 16; ++q) s[q] = csr16[off + e + q];
            unsigned u[16];
            #pragma unroll
            for (int q = 0; q < 16; ++q) u[q] = xbf[(size_t)s[q] * 64 + lane];
            #pragma unroll
            for (int q = 0; q < 16; ++q) {
                ax += __uint_as_float(u[q] << 16);
                ay += __uint_as_float(u[q] & 0xffff0000u);
            }
        }
        for (; e + 4 <= c; e += 4) {
            int s0 = csr16[off + e], s1 = csr16[off + e + 1];
            int s2 = csr16[off + e + 2], s3 = csr16[off + e + 3];
            unsigned u0 = xbf[(size_t)s0 * 64 + lane];
            unsigned u1 = xbf[(size_t)s1 * 64 + lane];
            unsigned u2 = xbf[(size_t)s2 * 64 + lane];
            unsigned u3 = xbf[(size_t)s3 * 64 + lane];
            ax += (__uint_as_float(u0 << 16) + __uint_as_float(u1 << 16)) +
                  (__uint_as_float(u2 << 16) + __uint_as_float(u3 << 16));
            ay += (__uint_as_float(u0 & 0xffff0000u) + __uint_as_float(u1 & 0xffff0000u)) +
                  (__uint_as_float(u2 & 0xffff0000u) + __uint_as_float(u3 & 0xffff0000u));
        }
        for (; e < c; ++e) {
            int s = csr16[off + e];
            unsigned u = xbf[(size_t)s * 64 + lane];
            ax += __uint_as_float(u << 16);
            ay += __uint_as_float(u & 0xffff0000u);
        }
        ushort hx = f32_to_bf16_bits(ax);
        ushort lx = f32_to_bf16_bits(ax - bf16bits_to_f32(hx));
        ushort hy = f32_to_bf16_bits(ay);
        ushort ly = f32_to_bf16_bits(ay - bf16bits_to_f32(hy));
        int row = wid * 4 + n;
        *(unsigned*)&sHi[row][2 * lane] = (unsigned)hx | ((unsigned)hy << 16);
        *(unsigned*)&sLo[row][2 * lane] = (unsigned)lx | ((unsigned)ly << 16);
    }
    __syncthreads();

    f32x4 accT[2];

    // ---- GEMM1: T = relu(h @ W1 + b1), wave computes f = {2*wid, 2*wid+1} ----
    {
        bf16x8 ahi[4], alo[4];
        #pragma unroll
        for (int t = 0; t < 4; ++t) {
            ahi[t] = *(bf16x8*)&sHi[lm][t * 32 + g * 8];
            alo[t] = *(bf16x8*)&sLo[lm][t * 32 + g * 8];
        }
        __syncthreads();   // all waves have read h before epilogue overwrites
        #pragma unroll
        for (int ff = 0; ff < 2; ++ff) {
            int f = wid * 2 + ff;
            const bf16x8* bh = (const bf16x8*)&w1hi[((size_t)(f * 4) * 64 + lane) * 8];
            const bf16x8* bl = (const bf16x8*)&w1lo[((size_t)(f * 4) * 64 + lane) * 8];
            f32x4 acc = {0.f, 0.f, 0.f, 0.f};
            #pragma unroll
            for (int t = 0; t < 4; ++t) {
                bf16x8 bhv = bh[t * 64];
                bf16x8 blv = bl[t * 64];
                acc = __builtin_amdgcn_mfma_f32_16x16x32_bf16(ahi[t], bhv, acc, 0, 0, 0);
                acc = __builtin_amdgcn_mfma_f32_16x16x32_bf16(alo[t], bhv, acc, 0, 0, 0);
                acc = __builtin_amdgcn_mfma_f32_16x16x32_bf16(ahi[t], blv, acc, 0, 0, 0);
            }
            accT[ff] = acc;
        }
    }
    // epilogue 1: bias+relu, split hi/lo, write back (C/D: row=g*4+r, col=f*16+lm)
    #pragma unroll
    for (int ff = 0; ff < 2; ++ff) {
        int f = wid * 2 + ff;
        float bv = b1[f * 16 + lm];
        #pragma unroll
        for (int r = 0; r < 4; ++r) {
            float v = accT[ff][r] + bv;
            v = v > 0.f ? v : 0.f;
            ushort hb = f32_to_bf16_bits(v);
            ushort lb = f32_to_bf16_bits(v - bf16bits_to_f32(hb));
            int m = g * 4 + r;
            sHi[m][f * 16 + lm] = (short)hb;
            sLo[m][f * 16 + lm] = (short)lb;
        }
    }
    __syncthreads();

    // ---- GEMM2: out = relu(T @ W2 + b2) ----
    {
        bf16x8 ahi[4], alo[4];
        #pragma unroll
        for (int t = 0; t < 4; ++t) {
            ahi[t] = *(bf16x8*)&sHi[lm][t * 32 + g * 8];
            alo[t] = *(bf16x8*)&sLo[lm][t * 32 + g * 8];
        }
        #pragma unroll
        for (int ff = 0; ff < 2; ++ff) {
            int f = wid * 2 + ff;
            const bf16x8* bh = (const bf16x8*)&w2hi[((size_t)(f * 4) * 64 + lane) * 8];
            const bf16x8* bl = (const bf16x8*)&w2lo[((size_t)(f * 4) * 64 + lane) * 8];
            f32x4 acc = {0.f, 0.f, 0.f, 0.f};
            #pragma unroll
            for (int t = 0; t < 4; ++t) {
                bf16x8 bhv = bh[t * 64];
                bf16x8 blv = bl[t * 64];
                acc = __builtin_amdgcn_mfma_f32_16x16x32_bf16(ahi[t], bhv, acc, 0, 0, 0);
                acc = __builtin_amdgcn_mfma_f32_16x16x32_bf16(alo[t], bhv, acc, 0, 0, 0);
                acc = __builtin_amdgcn_mfma_f32_16x16x32_bf16(ahi[t], blv, acc, 0, 0, 0);
            }
            accT[ff] = acc;
        }
    }
    // epilogue 2: bias+relu; store bf16 (next-layer gather) and/or f32 (final)
    #pragma unroll
    for (int ff = 0; ff < 2; ++ff) {
        int f = wid * 2 + ff;
        float bv = b2[f * 16 + lm];
        #pragma unroll
        for (int r = 0; r < 4; ++r) {
            float v = accT[ff][r] + bv;
            v = v > 0.f ? v : 0.f;
            int gn = nbase + g * 4 + r;
            size_t gi = (size_t)gn * HID + f * 16 + lm;
            if (xoutb) xoutb[gi] = f32_to_bf16_bits(v);
            if (xoutf) xoutf[gi] = v;
        }
    }
}

// ---------------- launch ----------------

extern "C" void kernel_launch(void* const* d_in, const int* in_sizes, int n_in,
                              void* d_out, int out_size, void* d_ws, size_t ws_size,
                              hipStream_t stream) {
    const float* feat = (const float*)d_in[0];
    const int* edge = (const int*)d_in[1];
    const int* src = edge;
    const int* dst = edge + N_EDGES;
    const float* W1a = (const float*)d_in[2];
    const float* b1a = (const float*)d_in[3];
    const float* W2a = (const float*)d_in[4];
    const float* b2a = (const float*)d_in[5];
    const float* Ws1 = (const float*)d_in[6];
    const float* bs1 = (const float*)d_in[7];
    const float* Ws2 = (const float*)d_in[8];
    const float* bs2 = (const float*)d_in[9];
    float* out = (float*)d_out;

    // ws layout (ints/halves, in order):
    //   cnt(50176 i32) | gcur(64 i32) | offs(50176) | cursor(50176)
    //   | csr16(800000 u16) | xbA(6.4M u16) | xbB | whi | wlo
    int* cnt = (int*)d_ws;
    int* gcur = cnt + 50176;
    int* offs = gcur + 64;
    int* cursor = offs + 50176;
    ushort* csr16 = (ushort*)(cursor + 50176);
    ushort* xbA = csr16 + N_EDGES;
    ushort* xbB = xbA + (size_t)N_NODES * HID;
    short* whi = (short*)(xbB + (size_t)N_NODES * HID);
    short* wlo = whi + 6 * 2048 * 8;

    hipMemsetAsync(cnt, 0, (50176 + 64) * sizeof(int), stream);

    prologue_kernel<<<1024, 256, 0, stream>>>(feat, dst, W1a, W2a, Ws1, Ws2,
                                              xbA, whi, wlo, cnt);
    alloc_offsets_kernel<<<(N_NODES + 255) / 256, 256, 0, stream>>>(cnt, offs, cursor, gcur);
    scatter_kernel<<<(N_EDGES + 255) / 256, 256, 0, stream>>>(src, dst, cursor, csr16);

    const int FB = N_NODES / 16;   // 3125 blocks, 16 nodes each, exact
    const int MS = 16384;          // per-matrix fragment array size (shorts)

    // mat order: W1a, W2a, Ws1[0], Ws2[0], Ws1[1], Ws2[1]
    // buffers: A(feat) -> B -> A -> d_out
    fused_gin_kernel<<<FB, 256, 0, stream>>>((const unsigned*)xbA, csr16, offs, cnt,
                                             whi + 0 * MS, wlo + 0 * MS,
                                             whi + 1 * MS, wlo + 1 * MS, b1a, b2a,
                                             xbB, nullptr);
    fused_gin_kernel<<<FB, 256, 0, stream>>>((const unsigned*)xbB, csr16, offs, cnt,
                                             whi + 2 * MS, wlo + 2 * MS,
                                             whi + 3 * MS, wlo + 3 * MS, bs1, bs2,
                                             xbA, nullptr);
    fused_gin_kernel<<<FB, 256, 0, stream>>>((const unsigned*)xbA, csr16, offs, cnt,
                                             whi + 4 * MS, wlo + 4 * MS,
                                             whi + 5 * MS, wlo + 5 * MS,
                                             bs1 + HID, bs2 + HID,
                                             nullptr, out);
}